// Round 2
// baseline (231.280 us; speedup 1.0000x reference)
//
#include <hip/hip_runtime.h>
#include <hip/hip_bf16.h>

typedef __attribute__((ext_vector_type(8))) short short8;
typedef __attribute__((ext_vector_type(4))) float f32x4;

#define MFMA16(a,b,c) __builtin_amdgcn_mfma_f32_16x16x32_bf16((a),(b),(c),0,0,0)

__device__ __forceinline__ ushort f2bf(float x) {
  union { float f; unsigned u; } v; v.f = x;
  unsigned u = v.u;
  u = (u + 0x7fffu + ((u >> 16) & 1u)) >> 16;
  return (ushort)u;
}

__device__ __forceinline__ short8 ld8(const ushort* p) {
  return *reinterpret_cast<const short8*>(p);
}

// ---- kernel 0: fp32 -> bf16 conversion of value, in_proj_w, out_w ----
__global__ void conv_kernel(const float* __restrict__ value,
                            const float* __restrict__ w_in,
                            const float* __restrict__ w_out,
                            ushort* __restrict__ vbf,
                            ushort* __restrict__ wbf,
                            ushort* __restrict__ owbf) {
  int i = blockIdx.x * 256 + threadIdx.x;
  if (i < 2097152) {
    vbf[i] = f2bf(value[i]);
  } else if (i < 2293760) {
    int j = i - 2097152; wbf[j] = f2bf(w_in[j]);
  } else {
    int j = i - 2293760; owbf[j] = f2bf(w_out[j]);
  }
}

// ---- kernel 1: qkv projection GEMM (8192x256)@(256x768)^T, scatter to head layouts ----
// qh[bh][n][d] (q pre-scaled by 1/sqrt(32)), kh[bh][n][d], vt[bh][d][n] (transposed for PV B-frags)
__global__ __launch_bounds__(256) void qkv_kernel(
    const ushort* __restrict__ vbf, const ushort* __restrict__ wbf,
    const float* __restrict__ bias,
    ushort* __restrict__ qh, ushort* __restrict__ kh, ushort* __restrict__ vt) {
  int tid = threadIdx.x;
  int wave = tid >> 6, lane = tid & 63;
  int lq = lane & 15, lg = lane >> 4;
  int r0 = blockIdx.x * 16;
  int c0 = (blockIdx.y * 4 + wave) * 16;
  f32x4 acc = {0.f, 0.f, 0.f, 0.f};
  const ushort* ap = vbf + (size_t)(r0 + lq) * 256 + lg * 8;
  const ushort* bp = wbf + (size_t)(c0 + lq) * 256 + lg * 8;
#pragma unroll
  for (int k0 = 0; k0 < 256; k0 += 32)
    acc = MFMA16(ld8(ap + k0), ld8(bp + k0), acc);
  int c = c0 + lq;
  float bv = bias[c];
#pragma unroll
  for (int r = 0; r < 4; ++r) {
    int row = r0 + lg * 4 + r;       // row = n*8 + b
    int n = row >> 3, b = row & 7;
    float v = acc[r] + bv;
    if (c < 256) {
      int h = c >> 5, d = c & 31;
      qh[((size_t)(b * 8 + h) * 1024 + n) * 32 + d] = f2bf(v * 0.17677669529663689f);
    } else if (c < 512) {
      int cc = c - 256, h = cc >> 5, d = cc & 31;
      kh[((size_t)(b * 8 + h) * 1024 + n) * 32 + d] = f2bf(v);
    } else {
      int cc = c - 512, h = cc >> 5, d = cc & 31;
      vt[((size_t)(b * 8 + h) * 32 + d) * 1024 + n] = f2bf(v);
    }
  }
}

// ---- kernel 2: fused attention. wg = (16-row block, batch b); loops all 8 heads.
// scores = sigmoid(clip(pos)) * exp(clip(content)-10), row-normalized (== reference softmax).
__global__ __launch_bounds__(256) void attn_kernel(
    const ushort* __restrict__ qh, const ushort* __restrict__ kh,
    const ushort* __restrict__ vt, const float* __restrict__ pos,
    ushort* __restrict__ ao, float* __restrict__ avg_out) {
  __shared__ __align__(16) ushort attn_lds[4][16][264];  // +8 pad: conflict-free b128 reads
  __shared__ float rowsum[4][16];
  __shared__ float pvred[4][16][32];

  int tid = threadIdx.x;
  int wave = tid >> 6, lane = tid & 63;
  int lq = lane & 15, lg = lane >> 4;
  int n0 = blockIdx.x * 16;
  int b = blockIdx.y;
  int mb = wave * 256;                 // this wave's m-range [mb, mb+256)

  float avg[16][4];
#pragma unroll
  for (int t = 0; t < 16; ++t)
#pragma unroll
    for (int r = 0; r < 4; ++r) avg[t][r] = 0.f;

  for (int h = 0; h < 8; ++h) {
    int bh = b * 8 + h;
    // ---- QK^T: S[n][m], 16 column-tiles of 16 per wave ----
    short8 qa = ld8(qh + ((size_t)bh * 1024 + n0 + lq) * 32 + lg * 8);
    const ushort* kp = kh + (size_t)bh * 32768 + lg * 8;
    f32x4 S[16];
#pragma unroll
    for (int t = 0; t < 16; ++t) {
      f32x4 z = {0.f, 0.f, 0.f, 0.f};
      S[t] = MFMA16(qa, ld8(kp + (size_t)(mb + t * 16 + lq) * 32), z);
    }
    // ---- gating + unnormalized weights + row-sum partials ----
    const float* pp = pos + (size_t)bh * 1048576;
    float rs[4] = {0.f, 0.f, 0.f, 0.f};
#pragma unroll
    for (int t = 0; t < 16; ++t) {
#pragma unroll
      for (int r = 0; r < 4; ++r) {
        int n = n0 + lg * 4 + r;
        int m = mb + t * 16 + lq;
        float p = pp[(size_t)n * 1024 + m];
        p = fminf(10.f, fmaxf(-10.f, p));
        float c = fminf(10.f, fmaxf(-10.f, S[t][r]));
        float w = __expf(c - 10.f) / (1.f + __expf(-p));
        S[t][r] = w;
        rs[r] += w;
      }
    }
    // reduce across the 16 lanes sharing the same rows
#pragma unroll
    for (int r = 0; r < 4; ++r) {
      rs[r] += __shfl_xor(rs[r], 1);
      rs[r] += __shfl_xor(rs[r], 2);
      rs[r] += __shfl_xor(rs[r], 4);
      rs[r] += __shfl_xor(rs[r], 8);
    }
    if (lq == 0) {
#pragma unroll
      for (int r = 0; r < 4; ++r) rowsum[wave][lg * 4 + r] = rs[r];
    }
    __syncthreads();
    float inv[4];
#pragma unroll
    for (int r = 0; r < 4; ++r) {
      int row = lg * 4 + r;
      inv[r] = 1.f / (rowsum[0][row] + rowsum[1][row] + rowsum[2][row] + rowsum[3][row]);
    }
    // ---- normalize, accumulate avg, stage attn (bf16) to LDS for PV ----
#pragma unroll
    for (int t = 0; t < 16; ++t) {
#pragma unroll
      for (int r = 0; r < 4; ++r) {
        float a = S[t][r] * inv[r];
        avg[t][r] += a;
        attn_lds[wave][lg * 4 + r][t * 16 + lq] = f2bf(a);
      }
    }
    __syncthreads();
    // ---- PV: partial over this wave's m-range, 2 d-tiles ----
    f32x4 acc0 = {0.f, 0.f, 0.f, 0.f}, acc1 = {0.f, 0.f, 0.f, 0.f};
    const ushort* vp = vt + (size_t)bh * 32768 + mb + lg * 8;
#pragma unroll
    for (int ks = 0; ks < 8; ++ks) {
      short8 pa = ld8(&attn_lds[wave][lq][ks * 32 + lg * 8]);
      acc0 = MFMA16(pa, ld8(vp + (size_t)lq * 1024 + ks * 32), acc0);
      acc1 = MFMA16(pa, ld8(vp + (size_t)(lq + 16) * 1024 + ks * 32), acc1);
    }
#pragma unroll
    for (int r = 0; r < 4; ++r) {
      pvred[wave][lg * 4 + r][lq] = acc0[r];
      pvred[wave][lg * 4 + r][lq + 16] = acc1[r];
    }
    __syncthreads();
    // ---- cross-wave reduce + store head output slice (bf16 scratch) ----
#pragma unroll
    for (int kk = 0; kk < 2; ++kk) {
      int id = tid + kk * 256;
      int n = id >> 5, d = id & 31;
      float s = pvred[0][n][d] + pvred[1][n][d] + pvred[2][n][d] + pvred[3][n][d];
      ao[((size_t)(n0 + n) * 8 + b) * 256 + h * 32 + d] = f2bf(s);
    }
    __syncthreads();
  }
  // ---- write averaged attention (mean over 8 heads), fp32 output ----
#pragma unroll
  for (int t = 0; t < 16; ++t)
#pragma unroll
    for (int r = 0; r < 4; ++r) {
      int n = n0 + lg * 4 + r, m = mb + t * 16 + lq;
      avg_out[(size_t)b * 1048576 + (size_t)n * 1024 + m] = avg[t][r] * 0.125f;
    }
}

// ---- kernel 3: output projection (8192x256)@(256x256)^T + bias -> d_out (fp32) ----
__global__ __launch_bounds__(256) void oproj_kernel(
    const ushort* __restrict__ ao, const ushort* __restrict__ owbf,
    const float* __restrict__ ob, float* __restrict__ outp) {
  int tid = threadIdx.x;
  int wave = tid >> 6, lane = tid & 63;
  int lq = lane & 15, lg = lane >> 4;
  int r0 = blockIdx.x * 16;
  int c0 = (blockIdx.y * 4 + wave) * 16;
  f32x4 acc = {0.f, 0.f, 0.f, 0.f};
  const ushort* ap = ao + (size_t)(r0 + lq) * 256 + lg * 8;
  const ushort* bp = owbf + (size_t)(c0 + lq) * 256 + lg * 8;
#pragma unroll
  for (int k0 = 0; k0 < 256; k0 += 32)
    acc = MFMA16(ld8(ap + k0), ld8(bp + k0), acc);
  int c = c0 + lq;
  float bv = ob[c];
#pragma unroll
  for (int r = 0; r < 4; ++r) {
    int row = r0 + lg * 4 + r;
    outp[(size_t)row * 256 + c] = acc[r] + bv;
  }
}

extern "C" void kernel_launch(void* const* d_in, const int* in_sizes, int n_in,
                              void* d_out, int out_size, void* d_ws, size_t ws_size,
                              hipStream_t stream) {
  const float* value = (const float*)d_in[0];
  const float* pos   = (const float*)d_in[1];
  const float* w_in  = (const float*)d_in[2];
  const float* b_in  = (const float*)d_in[3];
  const float* w_out = (const float*)d_in[4];
  const float* b_out = (const float*)d_in[5];

  char* ws = (char*)d_ws;
  ushort* vbf  = (ushort*)(ws);                 // 8192x256 bf16      (4 MB)
  ushort* wbf  = (ushort*)(ws + 4194304);       // 768x256 bf16       (384 KB)
  ushort* owbf = (ushort*)(ws + 4587520);       // 256x256 bf16       (128 KB)
  ushort* qh   = (ushort*)(ws + 4718592);       // 64x1024x32 bf16    (4 MB)
  ushort* kh   = (ushort*)(ws + 8912896);       // 64x1024x32 bf16    (4 MB)
  ushort* vt   = (ushort*)(ws + 13107200);      // 64x32x1024 bf16    (4 MB)
  ushort* ao   = (ushort*)(ws + 17301504);      // 8192x256 bf16      (4 MB)

  float* outp = (float*)d_out;                  // (N,B,E) fp32
  float* avgp = outp + 2097152;                 // (B,N,N) fp32

  conv_kernel<<<9216, 256, 0, stream>>>(value, w_in, w_out, vbf, wbf, owbf);
  qkv_kernel<<<dim3(512, 12), 256, 0, stream>>>(vbf, wbf, b_in, qh, kh, vt);
  attn_kernel<<<dim3(64, 8), 256, 0, stream>>>(qh, kh, vt, pos, ao, avgp);
  oproj_kernel<<<dim3(512, 4), 256, 0, stream>>>(ao, owbf, b_out, outp);
}

// Round 3
// 181.814 us; speedup vs baseline: 1.2721x; 1.2721x over previous
//
#include <hip/hip_runtime.h>
#include <hip/hip_bf16.h>

typedef __attribute__((ext_vector_type(8))) short short8;
typedef __attribute__((ext_vector_type(4))) float f32x4;
typedef __attribute__((ext_vector_type(4))) unsigned short u16x4;

#define MFMA16(a,b,c) __builtin_amdgcn_mfma_f32_16x16x32_bf16((a),(b),(c),0,0,0)

__device__ __forceinline__ ushort f2bf(float x) {
  union { float f; unsigned u; } v; v.f = x;
  unsigned u = v.u;
  u = (u + 0x7fffu + ((u >> 16) & 1u)) >> 16;
  return (ushort)u;
}

__device__ __forceinline__ short8 ld8(const ushort* p) {
  return *reinterpret_cast<const short8*>(p);
}

// ---- kernel 0: fp32 -> bf16 conversion (vectorized float4 -> ushort4) ----
__global__ void conv_kernel(const float* __restrict__ value,
                            const float* __restrict__ w_in,
                            const float* __restrict__ w_out,
                            ushort* __restrict__ vbf,
                            ushort* __restrict__ wbf,
                            ushort* __restrict__ owbf) {
  int i = blockIdx.x * 256 + threadIdx.x;   // float4 index
  const float* src; ushort* dst; int j;
  if (i < 524288)      { src = value; dst = vbf;  j = i; }
  else if (i < 573440) { src = w_in;  dst = wbf;  j = i - 524288; }
  else                 { src = w_out; dst = owbf; j = i - 573440; }
  float4 v = reinterpret_cast<const float4*>(src)[j];
  u16x4 o;
  o[0] = f2bf(v.x); o[1] = f2bf(v.y); o[2] = f2bf(v.z); o[3] = f2bf(v.w);
  reinterpret_cast<u16x4*>(dst)[j] = o;
}

// ---- kernel 1: qkv projection GEMM (8192x256)@(256x768)^T, scatter to head layouts ----
__global__ __launch_bounds__(256) void qkv_kernel(
    const ushort* __restrict__ vbf, const ushort* __restrict__ wbf,
    const float* __restrict__ bias,
    ushort* __restrict__ qh, ushort* __restrict__ kh, ushort* __restrict__ vt) {
  int tid = threadIdx.x;
  int wave = tid >> 6, lane = tid & 63;
  int lq = lane & 15, lg = lane >> 4;
  int r0 = blockIdx.x * 16;
  int c0 = (blockIdx.y * 4 + wave) * 16;
  f32x4 acc = {0.f, 0.f, 0.f, 0.f};
  const ushort* ap = vbf + (size_t)(r0 + lq) * 256 + lg * 8;
  const ushort* bp = wbf + (size_t)(c0 + lq) * 256 + lg * 8;
#pragma unroll
  for (int k0 = 0; k0 < 256; k0 += 32)
    acc = MFMA16(ld8(ap + k0), ld8(bp + k0), acc);
  int c = c0 + lq;
  float bv = bias[c];
#pragma unroll
  for (int r = 0; r < 4; ++r) {
    int row = r0 + lg * 4 + r;       // row = n*8 + b
    int n = row >> 3, b = row & 7;
    float v = acc[r] + bv;
    if (c < 256) {
      int h = c >> 5, d = c & 31;
      qh[((size_t)(b * 8 + h) * 1024 + n) * 32 + d] = f2bf(v * 0.17677669529663689f);
    } else if (c < 512) {
      int cc = c - 256, h = cc >> 5, d = cc & 31;
      kh[((size_t)(b * 8 + h) * 1024 + n) * 32 + d] = f2bf(v);
    } else {
      int cc = c - 512, h = cc >> 5, d = cc & 31;
      vt[((size_t)(b * 8 + h) * 32 + d) * 1024 + n] = f2bf(v);
    }
  }
}

// ---- kernel 2: fused attention. 512 threads = 8 waves; wave w owns m-chunk [w*128, w*128+128).
// Column permutation: tile t (t=0..7), col lq  <->  m = mb + lq*8 + t, so pos loads are float4.
__global__ __launch_bounds__(512, 4) void attn_kernel(
    const ushort* __restrict__ qh, const ushort* __restrict__ kh,
    const ushort* __restrict__ vt, const float* __restrict__ pos,
    ushort* __restrict__ ao, float* __restrict__ avg_out) {
  // attn staging [16][1028] ushort (32,896B) unioned with PV partials [8][16][32] f32 (16,384B)
  __shared__ __align__(16) unsigned char smem[16 * 1028 * 2 + 16 * 8 * 4];
  ushort (*attn_lds)[1028] = reinterpret_cast<ushort(*)[1028]>(smem);
  float  (*pvred)[16][32]  = reinterpret_cast<float(*)[16][32]>(smem);  // time-separated reuse
  float  (*rowsumT)[8]     = reinterpret_cast<float(*)[8]>(smem + 16 * 1028 * 2);

  int tid = threadIdx.x;
  int wave = tid >> 6, lane = tid & 63;
  int lq = lane & 15, lg = lane >> 4;
  int n0 = blockIdx.x * 16;
  int b = blockIdx.y;
  int mb = wave * 128;                 // this wave's m-range [mb, mb+128)

  float avg[8][4];
#pragma unroll
  for (int t = 0; t < 8; ++t)
#pragma unroll
    for (int r = 0; r < 4; ++r) avg[t][r] = 0.f;

  for (int h = 0; h < 8; ++h) {
    int bh = b * 8 + h;
    // ---- QK^T: S[t][r] = score(n = n0+lg*4+r, m = mb + lq*8 + t) ----
    short8 qa = ld8(qh + ((size_t)bh * 1024 + n0 + lq) * 32 + lg * 8);
    const ushort* kp = kh + (size_t)bh * 32768 + lg * 8;
    f32x4 S[8];
#pragma unroll
    for (int t = 0; t < 8; ++t) {
      f32x4 z = {0.f, 0.f, 0.f, 0.f};
      S[t] = MFMA16(qa, ld8(kp + (size_t)(mb + lq * 8 + t) * 32), z);
    }
    // ---- gating: w = sigmoid(clip(pos)) * exp(clip(content)-10); row-sum partials ----
    const float* pp = pos + (size_t)bh * 1048576;
    float rs[4] = {0.f, 0.f, 0.f, 0.f};
#pragma unroll
    for (int r = 0; r < 4; ++r) {
      int n = n0 + lg * 4 + r;
      const float* rowp = pp + (size_t)n * 1024 + mb + lq * 8;
      float4 p0 = *reinterpret_cast<const float4*>(rowp);
      float4 p1 = *reinterpret_cast<const float4*>(rowp + 4);
      float pv[8] = {p0.x, p0.y, p0.z, p0.w, p1.x, p1.y, p1.z, p1.w};
#pragma unroll
      for (int t = 0; t < 8; ++t) {
        float p = fminf(10.f, fmaxf(-10.f, pv[t]));
        float c = fminf(10.f, fmaxf(-10.f, S[t][r]));
        float w = __expf(c - 10.f) * __builtin_amdgcn_rcpf(1.f + __expf(-p));
        S[t][r] = w;
        rs[r] += w;
      }
    }
    // reduce across the 16 lanes sharing the same rows
#pragma unroll
    for (int r = 0; r < 4; ++r) {
      rs[r] += __shfl_xor(rs[r], 1);
      rs[r] += __shfl_xor(rs[r], 2);
      rs[r] += __shfl_xor(rs[r], 4);
      rs[r] += __shfl_xor(rs[r], 8);
    }
    if (lq == 0) {
#pragma unroll
      for (int r = 0; r < 4; ++r) rowsumT[lg * 4 + r][wave] = rs[r];
    }
    __syncthreads();                                   // bar1: rowsums ready
    float inv[4];
#pragma unroll
    for (int r = 0; r < 4; ++r) {
      int row = lg * 4 + r;
      float4 a0 = *reinterpret_cast<const float4*>(&rowsumT[row][0]);
      float4 a1 = *reinterpret_cast<const float4*>(&rowsumT[row][4]);
      inv[r] = __builtin_amdgcn_rcpf(a0.x + a0.y + a0.z + a0.w +
                                     a1.x + a1.y + a1.z + a1.w);
    }
    // ---- normalize, accumulate avg, stage attn (bf16, b128 stores) ----
#pragma unroll
    for (int r = 0; r < 4; ++r) {
      int row = lg * 4 + r;
      short8 pk;
#pragma unroll
      for (int t = 0; t < 8; ++t) {
        float a = S[t][r] * inv[r];
        avg[t][r] += a;
        pk[t] = (short)f2bf(a);
      }
      *reinterpret_cast<short8*>(&attn_lds[row][mb + lq * 8]) = pk;
    }
    __syncthreads();                                   // bar2: attn staged
    // ---- PV: partial over this wave's 128 columns, 2 d-tiles ----
    f32x4 acc0 = {0.f, 0.f, 0.f, 0.f}, acc1 = {0.f, 0.f, 0.f, 0.f};
    const ushort* vp = vt + (size_t)bh * 32768 + mb + lg * 8;
#pragma unroll
    for (int ks = 0; ks < 4; ++ks) {
      short8 pa = *reinterpret_cast<const short8*>(&attn_lds[lq][mb + ks * 32 + lg * 8]);
      acc0 = MFMA16(pa, ld8(vp + (size_t)lq * 1024 + ks * 32), acc0);
      acc1 = MFMA16(pa, ld8(vp + (size_t)(lq + 16) * 1024 + ks * 32), acc1);
    }
    __syncthreads();                                   // bar3: attn reads done (union safety)
#pragma unroll
    for (int r = 0; r < 4; ++r) {
      pvred[wave][lg * 4 + r][lq] = acc0[r];
      pvred[wave][lg * 4 + r][lq + 16] = acc1[r];
    }
    __syncthreads();                                   // bar4: partials ready
    // ---- cross-wave reduce + store head output slice (bf16 scratch) ----
    {
      int n = tid >> 5, d = tid & 31;
      float s = 0.f;
#pragma unroll
      for (int w = 0; w < 8; ++w) s += pvred[w][n][d];
      ao[((size_t)(n0 + n) * 8 + b) * 256 + h * 32 + d] = f2bf(s);
    }
  }
  // ---- write averaged attention (mean over 8 heads), fp32 float4 stores ----
#pragma unroll
  for (int r = 0; r < 4; ++r) {
    int n = n0 + lg * 4 + r;
    float* op = avg_out + (size_t)b * 1048576 + (size_t)n * 1024 + mb + lq * 8;
    float4 v0 = {avg[0][r] * 0.125f, avg[1][r] * 0.125f, avg[2][r] * 0.125f, avg[3][r] * 0.125f};
    float4 v1 = {avg[4][r] * 0.125f, avg[5][r] * 0.125f, avg[6][r] * 0.125f, avg[7][r] * 0.125f};
    *reinterpret_cast<float4*>(op) = v0;
    *reinterpret_cast<float4*>(op + 4) = v1;
  }
}

// ---- kernel 3: output projection (8192x256)@(256x256)^T + bias -> d_out (fp32) ----
__global__ __launch_bounds__(256) void oproj_kernel(
    const ushort* __restrict__ ao, const ushort* __restrict__ owbf,
    const float* __restrict__ ob, float* __restrict__ outp) {
  int tid = threadIdx.x;
  int wave = tid >> 6, lane = tid & 63;
  int lq = lane & 15, lg = lane >> 4;
  int r0 = blockIdx.x * 16;
  int c0 = (blockIdx.y * 4 + wave) * 16;
  f32x4 acc = {0.f, 0.f, 0.f, 0.f};
  const ushort* ap = ao + (size_t)(r0 + lq) * 256 + lg * 8;
  const ushort* bp = owbf + (size_t)(c0 + lq) * 256 + lg * 8;
#pragma unroll
  for (int k0 = 0; k0 < 256; k0 += 32)
    acc = MFMA16(ld8(ap + k0), ld8(bp + k0), acc);
  int c = c0 + lq;
  float bv = ob[c];
#pragma unroll
  for (int r = 0; r < 4; ++r) {
    int row = r0 + lg * 4 + r;
    outp[(size_t)row * 256 + c] = acc[r] + bv;
  }
}

extern "C" void kernel_launch(void* const* d_in, const int* in_sizes, int n_in,
                              void* d_out, int out_size, void* d_ws, size_t ws_size,
                              hipStream_t stream) {
  const float* value = (const float*)d_in[0];
  const float* pos   = (const float*)d_in[1];
  const float* w_in  = (const float*)d_in[2];
  const float* b_in  = (const float*)d_in[3];
  const float* w_out = (const float*)d_in[4];
  const float* b_out = (const float*)d_in[5];

  char* ws = (char*)d_ws;
  ushort* vbf  = (ushort*)(ws);                 // 8192x256 bf16      (4 MB)
  ushort* wbf  = (ushort*)(ws + 4194304);       // 768x256 bf16       (384 KB)
  ushort* owbf = (ushort*)(ws + 4587520);       // 256x256 bf16       (128 KB)
  ushort* qh   = (ushort*)(ws + 4718592);       // 64x1024x32 bf16    (4 MB)
  ushort* kh   = (ushort*)(ws + 8912896);       // 64x1024x32 bf16    (4 MB)
  ushort* vt   = (ushort*)(ws + 13107200);      // 64x32x1024 bf16    (4 MB)
  ushort* ao   = (ushort*)(ws + 17301504);      // 8192x256 bf16      (4 MB)

  float* outp = (float*)d_out;                  // (N,B,E) fp32
  float* avgp = outp + 2097152;                 // (B,N,N) fp32

  conv_kernel<<<2304, 256, 0, stream>>>(value, w_in, w_out, vbf, wbf, owbf);
  qkv_kernel<<<dim3(512, 12), 256, 0, stream>>>(vbf, wbf, b_in, qh, kh, vt);
  attn_kernel<<<dim3(64, 8), 512, 0, stream>>>(qh, kh, vt, pos, ao, avgp);
  oproj_kernel<<<dim3(512, 4), 256, 0, stream>>>(ao, owbf, b_out, outp);
}

// Round 4
// 181.784 us; speedup vs baseline: 1.2723x; 1.0002x over previous
//
#include <hip/hip_runtime.h>
#include <hip/hip_bf16.h>

typedef __attribute__((ext_vector_type(8))) short short8;
typedef __attribute__((ext_vector_type(4))) float f32x4;
typedef __attribute__((ext_vector_type(4))) unsigned short u16x4;

#define MFMA16(a,b,c) __builtin_amdgcn_mfma_f32_16x16x32_bf16((a),(b),(c),0,0,0)

__device__ __forceinline__ ushort f2bf(float x) {
  union { float f; unsigned u; } v; v.f = x;
  unsigned u = v.u;
  u = (u + 0x7fffu + ((u >> 16) & 1u)) >> 16;
  return (ushort)u;
}

__device__ __forceinline__ float bf2f(ushort u) {
  union { unsigned u; float f; } v; v.u = ((unsigned)u) << 16;
  return v.f;
}

__device__ __forceinline__ short8 ld8(const ushort* p) {
  return *reinterpret_cast<const short8*>(p);
}

// ---- kernel 0: fp32 -> bf16 conversion (vectorized float4 -> ushort4) ----
__global__ void conv_kernel(const float* __restrict__ value,
                            const float* __restrict__ w_in,
                            const float* __restrict__ w_out,
                            ushort* __restrict__ vbf,
                            ushort* __restrict__ wbf,
                            ushort* __restrict__ owbf) {
  int i = blockIdx.x * 256 + threadIdx.x;   // float4 index
  const float* src; ushort* dst; int j;
  if (i < 524288)      { src = value; dst = vbf;  j = i; }
  else if (i < 573440) { src = w_in;  dst = wbf;  j = i - 524288; }
  else                 { src = w_out; dst = owbf; j = i - 573440; }
  float4 v = reinterpret_cast<const float4*>(src)[j];
  u16x4 o;
  o[0] = f2bf(v.x); o[1] = f2bf(v.y); o[2] = f2bf(v.z); o[3] = f2bf(v.w);
  reinterpret_cast<u16x4*>(dst)[j] = o;
}

// ---- kernel 1: qkv projection GEMM (8192x256)@(256x768)^T, scatter to head layouts ----
// qh[bh][n][d] (q pre-scaled), kh[bh][n][d], vv[bh][n][d] (row-major; transposed later)
__global__ __launch_bounds__(256) void qkv_kernel(
    const ushort* __restrict__ vbf, const ushort* __restrict__ wbf,
    const float* __restrict__ bias,
    ushort* __restrict__ qh, ushort* __restrict__ kh, ushort* __restrict__ vv) {
  int tid = threadIdx.x;
  int wave = tid >> 6, lane = tid & 63;
  int lq = lane & 15, lg = lane >> 4;
  int r0 = blockIdx.x * 16;
  int c0 = (blockIdx.y * 4 + wave) * 16;
  f32x4 acc = {0.f, 0.f, 0.f, 0.f};
  const ushort* ap = vbf + (size_t)(r0 + lq) * 256 + lg * 8;
  const ushort* bp = wbf + (size_t)(c0 + lq) * 256 + lg * 8;
#pragma unroll
  for (int k0 = 0; k0 < 256; k0 += 32)
    acc = MFMA16(ld8(ap + k0), ld8(bp + k0), acc);
  int c = c0 + lq;
  float bv = bias[c];
#pragma unroll
  for (int r = 0; r < 4; ++r) {
    int row = r0 + lg * 4 + r;       // row = n*8 + b
    int n = row >> 3, b = row & 7;
    float v = acc[r] + bv;
    if (c < 256) {
      int h = c >> 5, d = c & 31;
      qh[((size_t)(b * 8 + h) * 1024 + n) * 32 + d] = f2bf(v * 0.17677669529663689f);
    } else if (c < 512) {
      int cc = c - 256, h = cc >> 5, d = cc & 31;
      kh[((size_t)(b * 8 + h) * 1024 + n) * 32 + d] = f2bf(v);
    } else {
      int cc = c - 512, h = cc >> 5, d = cc & 31;
      vv[((size_t)(b * 8 + h) * 1024 + n) * 32 + d] = f2bf(v);
    }
  }
}

// ---- kernel 1b: transpose vv[bh][m][d] -> vt[bh][d][m], coalesced both sides ----
__global__ __launch_bounds__(256) void vtrans_kernel(const ushort* __restrict__ vv,
                                                     ushort* __restrict__ vt) {
  __shared__ ushort t[32][73];   // pad 73: <=2-way bank aliasing both phases
  int tid = threadIdx.x;
  int bh = blockIdx.y, m0 = blockIdx.x * 64;
  int mm = tid >> 2, d0 = (tid & 3) * 8;
  short8 v = ld8(vv + ((size_t)bh * 1024 + m0 + mm) * 32 + d0);
#pragma unroll
  for (int j = 0; j < 8; ++j) t[d0 + j][mm] = (ushort)v[j];
  __syncthreads();
  int d = tid >> 3, mg = (tid & 7) * 8;
  short8 o;
#pragma unroll
  for (int j = 0; j < 8; ++j) o[j] = (short)t[d][mg + j];
  *reinterpret_cast<short8*>(vt + ((size_t)bh * 32 + d) * 1024 + m0 + mg) = o;
}

// ---- kernel 2: fused attention. 512 threads = 8 waves; wave owns m-chunk [w*128, w*128+128).
// Deferred normalization: PV runs on unnormalized w (bf16), scaled by inv afterwards.
// Column permutation: m = mb + lq*8 + t so pos loads are float4.
__global__ __launch_bounds__(512, 4) void attn_kernel(
    const ushort* __restrict__ qh, const ushort* __restrict__ kh,
    const ushort* __restrict__ vt, const float* __restrict__ pos,
    ushort* __restrict__ ao, float* __restrict__ avg_out) {
  __shared__ __align__(16) ushort attn_lds[16][1028];  // per-wave column slices
  __shared__ float pvred[8][16][32];
  __shared__ float rowsumT[16][8];

  int tid = threadIdx.x;
  int wave = tid >> 6, lane = tid & 63;
  int lq = lane & 15, lg = lane >> 4;
  int n0 = blockIdx.x * 16;
  int b = blockIdx.y;
  int mb = wave * 128;

  float avg[8][4];
#pragma unroll
  for (int t = 0; t < 8; ++t)
#pragma unroll
    for (int r = 0; r < 4; ++r) avg[t][r] = 0.f;

  for (int h = 0; h < 8; ++h) {
    int bh = b * 8 + h;
    short8 qa = ld8(qh + ((size_t)bh * 1024 + n0 + lq) * 32 + lg * 8);
    const ushort* kp = kh + (size_t)bh * 32768 + lg * 8;
    const float* pp = pos + ((size_t)bh << 20);
    float rs[4] = {0.f, 0.f, 0.f, 0.f};
    short8 wreg[4];

    // ---- phase A: tiles t=0..3 (m = mb + lq*8 + t), gate with first float4 ----
    {
      f32x4 S[4];
#pragma unroll
      for (int t = 0; t < 4; ++t) {
        f32x4 z = {0.f, 0.f, 0.f, 0.f};
        S[t] = MFMA16(qa, ld8(kp + (size_t)(mb + lq * 8 + t) * 32), z);
      }
#pragma unroll
      for (int r = 0; r < 4; ++r) {
        int n = n0 + lg * 4 + r;
        float4 p0 = *reinterpret_cast<const float4*>(pp + (size_t)n * 1024 + mb + lq * 8);
        float pv[4] = {p0.x, p0.y, p0.z, p0.w};
#pragma unroll
        for (int t = 0; t < 4; ++t) {
          float p = fminf(10.f, fmaxf(-10.f, pv[t]));
          float c = fminf(10.f, fmaxf(-10.f, S[t][r]));
          float w = __expf(c - 10.f) * __builtin_amdgcn_rcpf(1.f + __expf(-p));
          rs[r] += w;
          wreg[r][t] = (short)f2bf(w);
        }
      }
    }
    // ---- phase B: tiles t=4..7, gate with second float4 ----
    {
      f32x4 S[4];
#pragma unroll
      for (int t = 0; t < 4; ++t) {
        f32x4 z = {0.f, 0.f, 0.f, 0.f};
        S[t] = MFMA16(qa, ld8(kp + (size_t)(mb + lq * 8 + 4 + t) * 32), z);
      }
#pragma unroll
      for (int r = 0; r < 4; ++r) {
        int n = n0 + lg * 4 + r;
        float4 p1 = *reinterpret_cast<const float4*>(pp + (size_t)n * 1024 + mb + lq * 8 + 4);
        float pv[4] = {p1.x, p1.y, p1.z, p1.w};
#pragma unroll
        for (int t = 0; t < 4; ++t) {
          float p = fminf(10.f, fmaxf(-10.f, pv[t]));
          float c = fminf(10.f, fmaxf(-10.f, S[t][r]));
          float w = __expf(c - 10.f) * __builtin_amdgcn_rcpf(1.f + __expf(-p));
          rs[r] += w;
          wreg[r][4 + t] = (short)f2bf(w);
        }
      }
    }
    // ---- stage unnormalized w to LDS (XOR swizzle on column) ----
#pragma unroll
    for (int r = 0; r < 4; ++r) {
      int row = lg * 4 + r;
      int col = (mb + lq * 8) ^ ((row & 7) << 3);
      *reinterpret_cast<short8*>(&attn_lds[row][col]) = wreg[r];
    }
    // ---- rowsum partials -> LDS ----
#pragma unroll
    for (int r = 0; r < 4; ++r) {
      rs[r] += __shfl_xor(rs[r], 1);
      rs[r] += __shfl_xor(rs[r], 2);
      rs[r] += __shfl_xor(rs[r], 4);
      rs[r] += __shfl_xor(rs[r], 8);
    }
    if (lq == 0) {
#pragma unroll
      for (int r = 0; r < 4; ++r) rowsumT[lg * 4 + r][wave] = rs[r];
    }
    // ---- PV on unnormalized w: reads ONLY this wave's columns -> no barrier needed ----
    f32x4 acc0 = {0.f, 0.f, 0.f, 0.f}, acc1 = {0.f, 0.f, 0.f, 0.f};
    const ushort* vp = vt + (size_t)bh * 32768 + mb + lg * 8;
#pragma unroll
    for (int ks = 0; ks < 4; ++ks) {
      int col = (mb + ks * 32 + lg * 8) ^ ((lq & 7) << 3);
      short8 pa = *reinterpret_cast<const short8*>(&attn_lds[lq][col]);
      acc0 = MFMA16(pa, ld8(vp + (size_t)lq * 1024 + ks * 32), acc0);
      acc1 = MFMA16(pa, ld8(vp + (size_t)(lq + 16) * 1024 + ks * 32), acc1);
    }
    __syncthreads();                                   // bar1: rowsums visible
    float inv[4];
#pragma unroll
    for (int r = 0; r < 4; ++r) {
      int row = lg * 4 + r;
      float4 a0 = *reinterpret_cast<const float4*>(&rowsumT[row][0]);
      float4 a1 = *reinterpret_cast<const float4*>(&rowsumT[row][4]);
      inv[r] = __builtin_amdgcn_rcpf(a0.x + a0.y + a0.z + a0.w +
                                     a1.x + a1.y + a1.z + a1.w);
    }
    // ---- scale PV partials by inv, store; accumulate avg from wreg ----
#pragma unroll
    for (int r = 0; r < 4; ++r) {
      int row = lg * 4 + r;
      pvred[wave][row][lq] = acc0[r] * inv[r];
      pvred[wave][row][lq + 16] = acc1[r] * inv[r];
    }
#pragma unroll
    for (int r = 0; r < 4; ++r)
#pragma unroll
      for (int t = 0; t < 8; ++t)
        avg[t][r] += bf2f((ushort)wreg[r][t]) * inv[r];
    __syncthreads();                                   // bar2: partials ready
    // ---- cross-wave reduce + store head output slice ----
    {
      int n = tid >> 5, d = tid & 31;
      float s = 0.f;
#pragma unroll
      for (int w = 0; w < 8; ++w) s += pvred[w][n][d];
      ao[((size_t)(n0 + n) * 8 + b) * 256 + h * 32 + d] = f2bf(s);
    }
  }
  // ---- write averaged attention (mean over 8 heads), float4 stores ----
#pragma unroll
  for (int r = 0; r < 4; ++r) {
    int n = n0 + lg * 4 + r;
    float* op = avg_out + (size_t)b * 1048576 + (size_t)n * 1024 + mb + lq * 8;
    float4 v0 = {avg[0][r] * 0.125f, avg[1][r] * 0.125f, avg[2][r] * 0.125f, avg[3][r] * 0.125f};
    float4 v1 = {avg[4][r] * 0.125f, avg[5][r] * 0.125f, avg[6][r] * 0.125f, avg[7][r] * 0.125f};
    *reinterpret_cast<float4*>(op) = v0;
    *reinterpret_cast<float4*>(op + 4) = v1;
  }
}

// ---- kernel 3: output projection (8192x256)@(256x256)^T + bias -> d_out (fp32) ----
__global__ __launch_bounds__(256) void oproj_kernel(
    const ushort* __restrict__ ao, const ushort* __restrict__ owbf,
    const float* __restrict__ ob, float* __restrict__ outp) {
  int tid = threadIdx.x;
  int wave = tid >> 6, lane = tid & 63;
  int lq = lane & 15, lg = lane >> 4;
  int r0 = blockIdx.x * 16;
  int c0 = (blockIdx.y * 4 + wave) * 16;
  f32x4 acc = {0.f, 0.f, 0.f, 0.f};
  const ushort* ap = ao + (size_t)(r0 + lq) * 256 + lg * 8;
  const ushort* bp = owbf + (size_t)(c0 + lq) * 256 + lg * 8;
#pragma unroll
  for (int k0 = 0; k0 < 256; k0 += 32)
    acc = MFMA16(ld8(ap + k0), ld8(bp + k0), acc);
  int c = c0 + lq;
  float bv = ob[c];
#pragma unroll
  for (int r = 0; r < 4; ++r) {
    int row = r0 + lg * 4 + r;
    outp[(size_t)row * 256 + c] = acc[r] + bv;
  }
}

extern "C" void kernel_launch(void* const* d_in, const int* in_sizes, int n_in,
                              void* d_out, int out_size, void* d_ws, size_t ws_size,
                              hipStream_t stream) {
  const float* value = (const float*)d_in[0];
  const float* pos   = (const float*)d_in[1];
  const float* w_in  = (const float*)d_in[2];
  const float* b_in  = (const float*)d_in[3];
  const float* w_out = (const float*)d_in[4];
  const float* b_out = (const float*)d_in[5];

  char* ws = (char*)d_ws;
  ushort* vbf  = (ushort*)(ws);                 // 8192x256 bf16 (4 MB); reused as vt after qkv
  ushort* wbf  = (ushort*)(ws + 4194304);       // 768x256 bf16
  ushort* owbf = (ushort*)(ws + 4587520);       // 256x256 bf16
  ushort* qh   = (ushort*)(ws + 4718592);       // 64x1024x32 bf16 (4 MB)
  ushort* kh   = (ushort*)(ws + 8912896);       // 64x1024x32 bf16 (4 MB)
  ushort* vv   = (ushort*)(ws + 13107200);      // 64x1024x32 bf16 (4 MB, row-major V)
  ushort* vt   = (ushort*)(ws);                 // 64x32x1024 bf16 (4 MB, overlays dead vbf)
  ushort* ao   = (ushort*)(ws + 17301504);      // 8192x256 bf16 (4 MB)

  float* outp = (float*)d_out;                  // (N,B,E) fp32
  float* avgp = outp + 2097152;                 // (B,N,N) fp32

  conv_kernel<<<2304, 256, 0, stream>>>(value, w_in, w_out, vbf, wbf, owbf);
  qkv_kernel<<<dim3(512, 12), 256, 0, stream>>>(vbf, wbf, b_in, qh, kh, vv);
  vtrans_kernel<<<dim3(16, 64), 256, 0, stream>>>(vv, vt);
  attn_kernel<<<dim3(64, 8), 512, 0, stream>>>(qh, kh, vt, pos, ao, avgp);
  oproj_kernel<<<dim3(512, 4), 256, 0, stream>>>(ao, owbf, b_out, outp);
}